// Round 9
// baseline (162.320 us; speedup 1.0000x reference)
//
#include <hip/hip_runtime.h>
#include <hip/hip_bf16.h>

#define BB 64
#define PP 576
#define DD 1024
#define HH 512

typedef __attribute__((ext_vector_type(4))) float f32x4;
typedef __attribute__((ext_vector_type(8))) short bf16x8;

__device__ __forceinline__ unsigned short f2bf(float f) {
    union { float f; unsigned u; } v; v.f = f;
    unsigned r = v.u + 0x7FFF + ((v.u >> 16) & 1);
    return (unsigned short)(r >> 16);
}

__device__ __forceinline__ float fast_tanh(float x) {
    float e = __expf(2.f * x);
    return 1.f - 2.f / (e + 1.f);
}

// pack 8 f32 -> bf16x8 via HW packed convert (RNE)
__device__ __forceinline__ bf16x8 cvt8(f32x4 a, f32x4 b) {
    union { bf16x8 v; unsigned u[4]; } r;
    asm("v_cvt_pk_bf16_f32 %0, %1, %2" : "=v"(r.u[0]) : "v"(a.x), "v"(a.y));
    asm("v_cvt_pk_bf16_f32 %0, %1, %2" : "=v"(r.u[1]) : "v"(a.z), "v"(a.w));
    asm("v_cvt_pk_bf16_f32 %0, %1, %2" : "=v"(r.u[2]) : "v"(b.x), "v"(b.y));
    asm("v_cvt_pk_bf16_f32 %0, %1, %2" : "=v"(r.u[3]) : "v"(b.z), "v"(b.w));
    return r.v;
}

// ---- kernel 0: convert W_img fp32 -> bf16 in ws ----
__global__ __launch_bounds__(256) void k_convert(const float* __restrict__ w,
                                                 unsigned short* __restrict__ o) {
    int i = (blockIdx.x * 256 + threadIdx.x) * 4;
    f32x4 v = *(const f32x4*)(w + i);
    ushort4 r;
    r.x = f2bf(v.x); r.y = f2bf(v.y); r.z = f2bf(v.z); r.w = f2bf(v.w);
    *(ushort4*)(o + i) = r;
}

// ---- kernel 1: g[b][h] = tanh(seq[b]·W_seq[h]) * W_w[h]  (fp32 exact path) ----
__global__ __launch_bounds__(128) void k_seq(const float* __restrict__ seq,
                                             const float* __restrict__ W_seq,
                                             const float* __restrict__ W_w,
                                             float* __restrict__ g) {
    int b = blockIdx.x;
    int h = blockIdx.y * 128 + threadIdx.x;
    __shared__ float s_seq[DD];
    #pragma unroll
    for (int i = 0; i < 8; i++) s_seq[threadIdx.x + i * 128] = seq[b * DD + threadIdx.x + i * 128];
    __syncthreads();
    const float* wr = W_seq + (size_t)h * DD;
    float acc = 0.f;
    #pragma unroll 4
    for (int d = 0; d < DD; d += 4) {
        f32x4 w4 = *(const f32x4*)(wr + d);
        acc += w4.x * s_seq[d] + w4.y * s_seq[d + 1] + w4.z * s_seq[d + 2] + w4.w * s_seq[d + 3];
    }
    g[b * HH + h] = fast_tanh(acc) * W_w[h];
}

// ---- kernel 2: partial scores — A via LDS (r2 path), B DIRECT FROM L2 ----
// Block 256 thr = 4 waves. Tile BM=64 x HC=256, BK=64, 16 rounds.
// B (Wb, 1 MB, L2/L3-resident): loaded straight global->VGPR in MFMA fragment
//   layout (row h0+w*64+n*16+(l&15), k-chunk (l>>4)*8): 16 rows x 64B contiguous
//   per inst. No LDS staging, no barrier coupling -> loads pipeline freely
//   across rounds; latency hidden by wave overlap (m114).
// A: reg-stage fp32 (issue at round start, T14), cvt_pk pack, swizzled ds_write
//   into double-buffered As (2 x 8 KB). One __syncthreads per round.
// LDS = 16 KB total; occupancy VGPR-bound (~16 waves/CU).
__global__ __launch_bounds__(256) void k_scores(const float* __restrict__ img,
                                                const unsigned short* __restrict__ Wb,
                                                const float* __restrict__ g,
                                                float* __restrict__ sp) {
    int b = blockIdx.y;
    int rt = blockIdx.x % 9;
    int ch = blockIdx.x / 9;
    int p0 = rt * 64;
    int h0 = ch * 256;
    int tid = threadIdx.x;
    int w = tid >> 6, lane = tid & 63;
    int r15 = lane & 15;
    int kq = lane >> 4;

    __shared__ unsigned short As[2][64 * 64];   // 2 x 8 KB

    float gr[4];
    #pragma unroll
    for (int n = 0; n < 4; ++n) gr[n] = g[b * HH + h0 + w * 64 + n * 16 + r15];

    f32x4 acc[4][4];
    #pragma unroll
    for (int m = 0; m < 4; m++)
        #pragma unroll
        for (int n = 0; n < 4; n++) acc[m][n] = (f32x4)0.f;

    // A staging geometry (r2-proven): thread t -> row t>>2, 16 f32 at col (t&3)*16
    int ar = tid >> 2, acn = tid & 3;
    const float* asrc = img + ((size_t)(b * PP + p0 + ar)) * DD + acn * 16;
    int cp = acn * 2;
    int aw0 = ar * 64 + ((cp ^ (ar & 7)) * 8);
    int aw1 = ar * 64 + (((cp + 1) ^ (ar & 7)) * 8);

    // B fragment global base: row h0 + w*64 + r15 (+n*16), k = kr*64 + ks*32 + kq*8
    const unsigned short* bbase = Wb + (size_t)(h0 + w * 64 + r15) * DD + kq * 8;

    f32x4 ua[4];   // A prefetch registers (16 f32/thread)

    auto LOADA = [&](int t) {
        const float* s = asrc + t * 64;
        ua[0] = *(const f32x4*)s;
        ua[1] = *(const f32x4*)(s + 4);
        ua[2] = *(const f32x4*)(s + 8);
        ua[3] = *(const f32x4*)(s + 12);
    };
    auto PACKA = [&](int buf) {
        *(bf16x8*)&As[buf][aw0] = cvt8(ua[0], ua[1]);
        *(bf16x8*)&As[buf][aw1] = cvt8(ua[2], ua[3]);
    };

    // prologue: stage round 0
    LOADA(0);
    PACKA(0);
    __syncthreads();

    for (int kr = 0; kr < 16; ++kr) {
        int cur = kr & 1;
        if (kr < 15) {
            LOADA(kr + 1);                        // issue early; consumed after compute
            __builtin_amdgcn_sched_barrier(0);    // pin issue point before compute
        }
        #pragma unroll
        for (int ks = 0; ks < 2; ++ks) {
            int cbase = ks * 4 + kq;              // unswizzled 16B chunk 0..7
            bf16x8 af[4], bfv[4];
            #pragma unroll
            for (int n = 0; n < 4; ++n)
                bfv[n] = *(const bf16x8*)(bbase + (size_t)(n * 16) * DD + kr * 64 + ks * 32);
            #pragma unroll
            for (int m = 0; m < 4; ++m) {
                int row = m * 16 + r15;
                af[m] = *(const bf16x8*)&As[cur][row * 64 + ((cbase ^ (row & 7)) * 8)];
            }
            #pragma unroll
            for (int m = 0; m < 4; ++m)
                #pragma unroll
                for (int n = 0; n < 4; ++n)
                    acc[m][n] = __builtin_amdgcn_mfma_f32_16x16x32_bf16(af[m], bfv[n], acc[m][n], 0, 0, 0);
        }
        if (kr < 15) PACKA(cur ^ 1);              // wait on ua lands here (post-compute)
        __syncthreads();
    }

    // epilogue: tanh * g, reduce over this block's 256 cols
    float part[4][4];
    #pragma unroll
    for (int m = 0; m < 4; m++)
        #pragma unroll
        for (int j = 0; j < 4; j++) part[m][j] = 0.f;
    #pragma unroll
    for (int m = 0; m < 4; ++m)
        #pragma unroll
        for (int n = 0; n < 4; ++n) {
            float gv = gr[n];
            f32x4 v = acc[m][n];
            #pragma unroll
            for (int j = 0; j < 4; ++j) part[m][j] += fast_tanh(v[j]) * gv;
        }
    #pragma unroll
    for (int mask = 1; mask < 16; mask <<= 1)
        #pragma unroll
        for (int m = 0; m < 4; ++m)
            #pragma unroll
            for (int j = 0; j < 4; ++j)
                part[m][j] += __shfl_xor(part[m][j], mask, 64);

    float* red = (float*)&As[0][0];   // safe: last loop iter ended with __syncthreads
    if (r15 == 0) {
        int hi = lane >> 4;
        #pragma unroll
        for (int m = 0; m < 4; ++m)
            #pragma unroll
            for (int j = 0; j < 4; ++j)
                red[w * 64 + m * 16 + hi * 4 + j] = part[m][j];
    }
    __syncthreads();
    if (tid < 64) {
        float s = red[tid] + red[64 + tid] + red[128 + tid] + red[192 + tid];
        sp[(size_t)ch * (BB * PP) + b * PP + p0 + tid] = s;
    }
}

// ---- kernel 3: sum the 2 col-half partials + softmax over P per batch ----
__global__ __launch_bounds__(576) void k_softmax(const float* __restrict__ sp,
                                                 float* __restrict__ alpha) {
    int b = blockIdx.x;
    int t = threadIdx.x;  // 0..575
    __shared__ float red[9];
    float s = sp[b * PP + t] + sp[BB * PP + b * PP + t];
    float m = s;
    #pragma unroll
    for (int off = 32; off; off >>= 1) m = fmaxf(m, __shfl_xor(m, off, 64));
    int w = t >> 6;
    if ((t & 63) == 0) red[w] = m;
    __syncthreads();
    float gm = red[0];
    #pragma unroll
    for (int i = 1; i < 9; i++) gm = fmaxf(gm, red[i]);
    float e = __expf(s - gm);
    float sum = e;
    #pragma unroll
    for (int off = 32; off; off >>= 1) sum += __shfl_xor(sum, off, 64);
    __syncthreads();
    if ((t & 63) == 0) red[w] = sum;
    __syncthreads();
    float gsum = 0.f;
    #pragma unroll
    for (int i = 0; i < 9; i++) gsum += red[i];
    alpha[b * PP + t] = e / gsum;
}

// ---- kernel 4: partial weighted sums over 64-patch chunks ----
__global__ __launch_bounds__(256) void k_attend(const float* __restrict__ img,
                                                const float* __restrict__ alpha,
                                                float* __restrict__ part) {
    int b = blockIdx.y;
    int pc = blockIdx.x;  // 0..8
    int t = threadIdx.x;
    __shared__ float al[64];
    if (t < 64) al[t] = alpha[b * PP + pc * 64 + t];
    __syncthreads();
    int d = t * 4;
    f32x4 acc = (f32x4)0.f;
    const float* base = img + ((size_t)b * PP + (size_t)pc * 64) * DD + d;
    #pragma unroll 4
    for (int i = 0; i < 64; i++) {
        f32x4 v = *(const f32x4*)(base + (size_t)i * DD);
        acc += al[i] * v;
    }
    float* o = part + ((size_t)pc * BB + b) * DD + d;
    *(f32x4*)o = acc;
}

// ---- kernel 5: reduce the 9 partials ----
__global__ __launch_bounds__(256) void k_reduce(const float* __restrict__ part,
                                                float* __restrict__ out) {
    int i = blockIdx.x * 256 + threadIdx.x;  // 0..65535
    float s = 0.f;
    #pragma unroll
    for (int pc = 0; pc < 9; pc++) s += part[pc * (BB * DD) + i];
    out[i] = s;
}

extern "C" void kernel_launch(void* const* d_in, const int* in_sizes, int n_in,
                              void* d_out, int out_size, void* d_ws, size_t ws_size,
                              hipStream_t stream) {
    const float* seq   = (const float*)d_in[0];   // [64,1024]
    const float* img   = (const float*)d_in[1];   // [64,576,1024]
    const float* W_seq = (const float*)d_in[2];   // [512,1024]
    const float* W_img = (const float*)d_in[3];   // [512,1024]
    const float* W_w   = (const float*)d_in[4];   // [1,512]
    float* out = (float*)d_out;                   // [64,1024]

    char* ws = (char*)d_ws;
    unsigned short* Wb = (unsigned short*)ws;                        // 1 MB
    float* g      = (float*)(ws + 1048576);                          // 128 KB
    float* sp     = (float*)(ws + 1048576 + 131072);                 // 2*144 KB (partial scores)
    float* alpha  = (float*)(ws + 1048576 + 131072 + 294912);        // 144 KB
    float* part   = (float*)(ws + 1048576 + 131072 + 294912 + 147456); // 2.25 MB

    k_convert<<<512, 256, 0, stream>>>(W_img, Wb);
    k_seq<<<dim3(BB, 4), 128, 0, stream>>>(seq, W_seq, W_w, g);
    k_scores<<<dim3(18, BB), 256, 0, stream>>>(img, Wb, g, sp);
    k_softmax<<<BB, 576, 0, stream>>>(sp, alpha);
    k_attend<<<dim3(9, BB), 256, 0, stream>>>(img, alpha, part);
    k_reduce<<<256, 256, 0, stream>>>(part, out);
}

// Round 10
// 157.147 us; speedup vs baseline: 1.0329x; 1.0329x over previous
//
#include <hip/hip_runtime.h>
#include <hip/hip_bf16.h>

#define BB 64
#define PP 576
#define DD 1024
#define HH 512

typedef __attribute__((ext_vector_type(4))) float f32x4;
typedef __attribute__((ext_vector_type(8))) short bf16x8;

__device__ __forceinline__ unsigned short f2bf(float f) {
    union { float f; unsigned u; } v; v.f = f;
    unsigned r = v.u + 0x7FFF + ((v.u >> 16) & 1);
    return (unsigned short)(r >> 16);
}

__device__ __forceinline__ float fast_tanh(float x) {
    float e = __expf(2.f * x);
    return 1.f - 2.f / (e + 1.f);
}

__device__ __forceinline__ void gload16(const void* g, void* l) {
    __builtin_amdgcn_global_load_lds((const __attribute__((address_space(1))) unsigned int*)g,
                                     (__attribute__((address_space(3))) unsigned int*)l,
                                     16, 0, 0);
}

// pack 8 f32 -> bf16x8 via HW packed convert (RNE)
__device__ __forceinline__ bf16x8 cvt8(f32x4 a, f32x4 b) {
    union { bf16x8 v; unsigned u[4]; } r;
    asm("v_cvt_pk_bf16_f32 %0, %1, %2" : "=v"(r.u[0]) : "v"(a.x), "v"(a.y));
    asm("v_cvt_pk_bf16_f32 %0, %1, %2" : "=v"(r.u[1]) : "v"(a.z), "v"(a.w));
    asm("v_cvt_pk_bf16_f32 %0, %1, %2" : "=v"(r.u[2]) : "v"(b.x), "v"(b.y));
    asm("v_cvt_pk_bf16_f32 %0, %1, %2" : "=v"(r.u[3]) : "v"(b.z), "v"(b.w));
    return r.v;
}

// ---- kernel 0: convert W_img fp32 -> bf16 in ws ----
__global__ __launch_bounds__(256) void k_convert(const float* __restrict__ w,
                                                 unsigned short* __restrict__ o) {
    int i = (blockIdx.x * 256 + threadIdx.x) * 4;
    f32x4 v = *(const f32x4*)(w + i);
    ushort4 r;
    r.x = f2bf(v.x); r.y = f2bf(v.y); r.z = f2bf(v.z); r.w = f2bf(v.w);
    *(ushort4*)(o + i) = r;
}

// ---- kernel 1: g[b][h] = tanh(seq[b]·W_seq[h]) * W_w[h]  (fp32 exact path) ----
__global__ __launch_bounds__(128) void k_seq(const float* __restrict__ seq,
                                             const float* __restrict__ W_seq,
                                             const float* __restrict__ W_w,
                                             float* __restrict__ g) {
    int b = blockIdx.x;
    int h = blockIdx.y * 128 + threadIdx.x;
    __shared__ float s_seq[DD];
    #pragma unroll
    for (int i = 0; i < 8; i++) s_seq[threadIdx.x + i * 128] = seq[b * DD + threadIdx.x + i * 128];
    __syncthreads();
    const float* wr = W_seq + (size_t)h * DD;
    float acc = 0.f;
    #pragma unroll 4
    for (int d = 0; d < DD; d += 4) {
        f32x4 w4 = *(const f32x4*)(wr + d);
        acc += w4.x * s_seq[d] + w4.y * s_seq[d + 1] + w4.z * s_seq[d + 2] + w4.w * s_seq[d + 3];
    }
    g[b * HH + h] = fast_tanh(acc) * W_w[h];
}

// ---- kernel 2: partial scores — r2 schedule, BM=128, 8 waves ----
// Block 512 thr = 8 waves (wr=w>>2 in {0,1}: row half; wc=w&3: col group).
// Tile BM=128 x HC=256, BK=64, 16 rounds, single-buffered, 2 barriers/round —
// byte-for-byte the round-2 per-wave schedule (the only structure that ever
// worked; r3-r9 pipelining variants all regressed). BM=128 halves B-staging
// bytes and barrier count PER FLOP; cvt_pk halves the A-pack VALU cost.
// LDS = As 16KB + Bs 32KB = 48KB. P=576 -> 5 row-tiles (last half, clamped).
__global__ __launch_bounds__(512) void k_scores(const float* __restrict__ img,
                                                const unsigned short* __restrict__ Wb,
                                                const float* __restrict__ g,
                                                float* __restrict__ sp) {
    int b = blockIdx.y;
    int rt = blockIdx.x >> 1;     // 0..4
    int ch = blockIdx.x & 1;      // 0..1
    int p0 = rt * 128;
    int h0 = ch * 256;
    int tid = threadIdx.x;        // 0..511
    int w = tid >> 6, lane = tid & 63;
    int wr = w >> 2, wc = w & 3;
    int r15 = lane & 15;
    int kq = lane >> 4;

    __shared__ unsigned short As[128 * 64];   // 16 KB
    __shared__ unsigned short Bs[256 * 64];   // 32 KB

    float gr[4];
    #pragma unroll
    for (int n = 0; n < 4; ++n) gr[n] = g[b * HH + h0 + wc * 64 + n * 16 + r15];

    f32x4 acc[4][4];
    #pragma unroll
    for (int m = 0; m < 4; m++)
        #pragma unroll
        for (int n = 0; n < 4; n++) acc[m][n] = (f32x4)0.f;

    // A staging: thread t -> row t>>2 (0..127), 16 f32 at col (t&3)*16
    int ar = tid >> 2, acn = tid & 3;
    int prow = p0 + ar; if (prow > PP - 1) prow = PP - 1;   // tail clamp
    const float* asrc = img + ((size_t)(b * PP + prow)) * DD + acn * 16;
    int cp = acn * 2;
    int aw0 = ar * 64 + ((cp ^ (ar & 7)) * 8);
    int aw1 = ar * 64 + (((cp + 1) ^ (ar & 7)) * 8);

    // B staging: wave w stages rows [w*32, w*32+32): 4 issues x 8 rows
    int brow_l = lane >> 3;   // 0..7
    int bchunk = lane & 7;    // 16B chunk within 128B row

    for (int kr = 0; kr < 16; ++kr) {
        int k0 = kr * 64;
        if (kr) __syncthreads();
        // B: 4 wave-issues x 1KB, linear LDS dest, swizzled global source
        #pragma unroll
        for (int i = 0; i < 4; ++i) {
            int hr = w * 32 + i * 8 + brow_l;
            const unsigned short* src = Wb + (size_t)(h0 + hr) * DD + k0 + ((bchunk ^ (hr & 7)) * 8);
            gload16(src, &Bs[(w * 32 + i * 8) * 64]);
        }
        // A: 16 f32 -> cvt_pk -> 2 swizzled ds_writes
        f32x4 v0 = *(const f32x4*)(asrc + k0);
        f32x4 v1 = *(const f32x4*)(asrc + k0 + 4);
        f32x4 v2 = *(const f32x4*)(asrc + k0 + 8);
        f32x4 v3 = *(const f32x4*)(asrc + k0 + 12);
        *(bf16x8*)&As[aw0] = cvt8(v0, v1);
        *(bf16x8*)&As[aw1] = cvt8(v2, v3);
        __syncthreads();   // drains vmcnt (gload_lds) + lgkm (ds_write)

        #pragma unroll
        for (int ks = 0; ks < 2; ++ks) {
            int cbase = ks * 4 + kq;   // 16B chunk index 0..7
            bf16x8 af[4], bfv[4];
            #pragma unroll
            for (int m = 0; m < 4; ++m) {
                int row = wr * 64 + m * 16 + r15;     // row&7 == r15&7
                af[m] = *(const bf16x8*)&As[row * 64 + ((cbase ^ (r15 & 7)) * 8)];
            }
            #pragma unroll
            for (int n = 0; n < 4; ++n) {
                int hr = wc * 64 + n * 16 + r15;      // hr&7 == r15&7
                bfv[n] = *(const bf16x8*)&Bs[hr * 64 + ((cbase ^ (r15 & 7)) * 8)];
            }
            #pragma unroll
            for (int m = 0; m < 4; ++m)
                #pragma unroll
                for (int n = 0; n < 4; ++n)
                    acc[m][n] = __builtin_amdgcn_mfma_f32_16x16x32_bf16(af[m], bfv[n], acc[m][n], 0, 0, 0);
        }
    }

    // epilogue: tanh * g, reduce over this block's 256 cols
    float part[4][4];
    #pragma unroll
    for (int m = 0; m < 4; m++)
        #pragma unroll
        for (int j = 0; j < 4; j++) part[m][j] = 0.f;
    #pragma unroll
    for (int m = 0; m < 4; ++m)
        #pragma unroll
        for (int n = 0; n < 4; ++n) {
            float gv = gr[n];
            f32x4 v = acc[m][n];
            #pragma unroll
            for (int j = 0; j < 4; ++j) part[m][j] += fast_tanh(v[j]) * gv;
        }
    #pragma unroll
    for (int mask = 1; mask < 16; mask <<= 1)
        #pragma unroll
        for (int m = 0; m < 4; ++m)
            #pragma unroll
            for (int j = 0; j < 4; ++j)
                part[m][j] += __shfl_xor(part[m][j], mask, 64);

    __syncthreads();                 // all waves done reading As/Bs
    float* red = (float*)As;         // alias 2KB scratch onto As
    if (r15 == 0) {
        int hi = lane >> 4;
        #pragma unroll
        for (int m = 0; m < 4; ++m)
            #pragma unroll
            for (int j = 0; j < 4; ++j)
                red[(wr * 4 + wc) * 64 + m * 16 + hi * 4 + j] = part[m][j];
    }
    __syncthreads();
    if (tid < 128 && p0 + tid < PP) {
        int wrt = tid >> 6, r = tid & 63;
        float s = red[(wrt * 4 + 0) * 64 + r] + red[(wrt * 4 + 1) * 64 + r]
                + red[(wrt * 4 + 2) * 64 + r] + red[(wrt * 4 + 3) * 64 + r];
        sp[(size_t)ch * (BB * PP) + b * PP + p0 + tid] = s;
    }
}

// ---- kernel 3: sum the 2 col-half partials + softmax over P per batch ----
__global__ __launch_bounds__(576) void k_softmax(const float* __restrict__ sp,
                                                 float* __restrict__ alpha) {
    int b = blockIdx.x;
    int t = threadIdx.x;  // 0..575
    __shared__ float red[9];
    float s = sp[b * PP + t] + sp[BB * PP + b * PP + t];
    float m = s;
    #pragma unroll
    for (int off = 32; off; off >>= 1) m = fmaxf(m, __shfl_xor(m, off, 64));
    int w = t >> 6;
    if ((t & 63) == 0) red[w] = m;
    __syncthreads();
    float gm = red[0];
    #pragma unroll
    for (int i = 1; i < 9; i++) gm = fmaxf(gm, red[i]);
    float e = __expf(s - gm);
    float sum = e;
    #pragma unroll
    for (int off = 32; off; off >>= 1) sum += __shfl_xor(sum, off, 64);
    __syncthreads();
    if ((t & 63) == 0) red[w] = sum;
    __syncthreads();
    float gsum = 0.f;
    #pragma unroll
    for (int i = 0; i < 9; i++) gsum += red[i];
    alpha[b * PP + t] = e / gsum;
}

// ---- kernel 4: partial weighted sums over 64-patch chunks ----
__global__ __launch_bounds__(256) void k_attend(const float* __restrict__ img,
                                                const float* __restrict__ alpha,
                                                float* __restrict__ part) {
    int b = blockIdx.y;
    int pc = blockIdx.x;  // 0..8
    int t = threadIdx.x;
    __shared__ float al[64];
    if (t < 64) al[t] = alpha[b * PP + pc * 64 + t];
    __syncthreads();
    int d = t * 4;
    f32x4 acc = (f32x4)0.f;
    const float* base = img + ((size_t)b * PP + (size_t)pc * 64) * DD + d;
    #pragma unroll 4
    for (int i = 0; i < 64; i++) {
        f32x4 v = *(const f32x4*)(base + (size_t)i * DD);
        acc += al[i] * v;
    }
    float* o = part + ((size_t)pc * BB + b) * DD + d;
    *(f32x4*)o = acc;
}

// ---- kernel 5: reduce the 9 partials ----
__global__ __launch_bounds__(256) void k_reduce(const float* __restrict__ part,
                                                float* __restrict__ out) {
    int i = blockIdx.x * 256 + threadIdx.x;  // 0..65535
    float s = 0.f;
    #pragma unroll
    for (int pc = 0; pc < 9; pc++) s += part[pc * (BB * DD) + i];
    out[i] = s;
}

extern "C" void kernel_launch(void* const* d_in, const int* in_sizes, int n_in,
                              void* d_out, int out_size, void* d_ws, size_t ws_size,
                              hipStream_t stream) {
    const float* seq   = (const float*)d_in[0];   // [64,1024]
    const float* img   = (const float*)d_in[1];   // [64,576,1024]
    const float* W_seq = (const float*)d_in[2];   // [512,1024]
    const float* W_img = (const float*)d_in[3];   // [512,1024]
    const float* W_w   = (const float*)d_in[4];   // [1,512]
    float* out = (float*)d_out;                   // [64,1024]

    char* ws = (char*)d_ws;
    unsigned short* Wb = (unsigned short*)ws;                        // 1 MB
    float* g      = (float*)(ws + 1048576);                          // 128 KB
    float* sp     = (float*)(ws + 1048576 + 131072);                 // 2*144 KB (partial scores)
    float* alpha  = (float*)(ws + 1048576 + 131072 + 294912);        // 144 KB
    float* part   = (float*)(ws + 1048576 + 131072 + 294912 + 147456); // 2.25 MB

    k_convert<<<512, 256, 0, stream>>>(W_img, Wb);
    k_seq<<<dim3(BB, 4), 128, 0, stream>>>(seq, W_seq, W_w, g);
    k_scores<<<dim3(10, BB), 512, 0, stream>>>(img, Wb, g, sp);
    k_softmax<<<BB, 576, 0, stream>>>(sp, alpha);
    k_attend<<<dim3(9, BB), 256, 0, stream>>>(img, alpha, part);
    k_reduce<<<256, 256, 0, stream>>>(part, out);
}